// Round 8
// baseline (157.024 us; speedup 1.0000x reference)
//
#include <hip/hip_runtime.h>
#include <hip/hip_cooperative_groups.h>
#include <float.h>
#include <limits.h>
#include <math.h>

namespace cg = cooperative_groups;

// Fixed problem shapes
constexpr int kB = 24;
constexpr int kC = 4;
constexpr int kHW = 65536;              // 256*256
constexpr int kD = 64;
constexpr int kNChunk = 32;
constexpr int kChunk = kHW / kNChunk;   // 2048 pixels per chunk-block
constexpr int kWaves = 4;               // waves per block
constexpr int kMaxS = 8;                // supports sample_num <= 8 (actual 5)
constexpr int kSlotsPerBatch = kNChunk * kWaves * kMaxS;    // 1024
constexpr float kTau = 0.07f;
constexpr float kEpsLog = 1e-6f;
constexpr float kEpsDen = 1e-8f;
constexpr float kEpsNorm = 1e-12f;

// ---- packed ordering key: high32 = monotone-mapped float (desc), low32 = ~pix (idx asc) ----
__device__ __forceinline__ unsigned long long packKey(float v, unsigned int pix) {
    unsigned int x = __float_as_uint(v);
    unsigned int m = x ^ (((unsigned int)((int)x >> 31)) | 0x80000000u);  // branchless monotone map
    return ((unsigned long long)m << 32) | (unsigned long long)(~pix);
}

__device__ __forceinline__ unsigned long long u64max(unsigned long long a, unsigned long long b) {
    return a > b ? a : b;
}

__device__ __forceinline__ unsigned long long shfl_xor_u64(unsigned long long k, int m) {
    int lo = __shfl_xor((int)(unsigned int)k, m, 64);
    int hi = __shfl_xor((int)(unsigned int)(k >> 32), m, 64);
    return ((unsigned long long)(unsigned int)hi << 32) | (unsigned long long)(unsigned int)lo;
}

__device__ __forceinline__ unsigned long long waveMax64(unsigned long long k) {
    #pragma unroll
    for (int o = 32; o > 0; o >>= 1) k = u64max(k, shfl_xor_u64(k, o));
    return k;
}

__device__ __forceinline__ float wave_sum(float x) {
    #pragma unroll
    for (int o = 32; o > 0; o >>= 1) x += __shfl_xor(x, o, 64);
    return x;
}

// ---------------------------------------------------------------------------
// ONE cooperative kernel, ONE graph node. grid = kB*kNChunk = 768 blocks x 256.
// Phase A: every wave computes top-S over its 512 pixels, plain-stores S keys.
// grid.sync()  (CG handles cross-XCD release/acquire)
// Phase B: wave 0 of blocks 0..23 merges batch b's 1024 slots, gathers 3xS
//          proj vectors, computes the contrastive loss -> per_b[b].
// grid.sync()
// Phase C: block 0 thread 0: deterministic serial b=0..23 sum -> out[0].
// No atomics, no counters, no persistent state: fully deterministic.
// ---------------------------------------------------------------------------
__global__ __launch_bounds__(256) void k_fused(
        const float* __restrict__ pred, const float* __restrict__ proj,
        const int* __restrict__ idxp, const int* __restrict__ snum,
        unsigned long long* __restrict__ cand,
        float* __restrict__ per_b, float* __restrict__ out) {
    cg::grid_group grid = cg::this_grid();

    int S = snum[0];
    S = S < 1 ? 1 : (S > kMaxS ? kMaxS : S);
    const int t = threadIdx.x;
    const int lane = t & 63;
    const int wave = t >> 6;

    // ================= Phase A: per-wave top-S =================
    {
        const int b = blockIdx.x / kNChunk;
        const int chunk = blockIdx.x % kNChunk;
        const int j0 = chunk * kChunk + t * 8;          // 8 consecutive pixels/thread
        const float* pb = pred + (size_t)b * kC * kHW + j0;

        float u[8];
        #pragma unroll
        for (int i = 0; i < 8; ++i) u[i] = 0.f;
        #pragma unroll
        for (int c = 0; c < kC; ++c) {
            float4 a = *reinterpret_cast<const float4*>(pb + (size_t)c * kHW);
            float4 d = *reinterpret_cast<const float4*>(pb + (size_t)c * kHW + 4);
            u[0] += a.x * __logf(a.x + kEpsLog);
            u[1] += a.y * __logf(a.y + kEpsLog);
            u[2] += a.z * __logf(a.z + kEpsLog);
            u[3] += a.w * __logf(a.w + kEpsLog);
            u[4] += d.x * __logf(d.x + kEpsLog);
            u[5] += d.y * __logf(d.y + kEpsLog);
            u[6] += d.z * __logf(d.z + kEpsLog);
            u[7] += d.w * __logf(d.w + kEpsLog);
        }
        unsigned long long key[8];
        #pragma unroll
        for (int i = 0; i < 8; ++i) key[i] = packKey(u[i], (unsigned int)(j0 + i));

        unsigned long long* myCand = cand + ((size_t)blockIdx.x * kWaves + wave) * kMaxS;
        for (int r = 0; r < S; ++r) {
            unsigned long long my = key[0];
            #pragma unroll
            for (int i = 1; i < 8; ++i) my = u64max(my, key[i]);
            const unsigned long long w = waveMax64(my);
            if (lane == 0) myCand[r] = w;
            #pragma unroll
            for (int i = 0; i < 8; ++i) if (key[i] == w) key[i] = 0ull;
        }
    }

    grid.sync();

    // ================= Phase B: per-batch merge + loss (blocks 0..23, wave 0) ====
    if (blockIdx.x < kB && t < 64) {
        const int b = blockIdx.x;

        const unsigned long long* bc = cand + (size_t)b * kSlotsPerBatch;
        unsigned long long c[16];
        #pragma unroll
        for (int k = 0; k < 16; ++k) {
            const int sid = lane + 64 * k;
            const unsigned long long v = bc[sid];
            c[k] = ((sid & (kMaxS - 1)) < S) ? v : 0ull;   // mask slots never written
        }
        int topPix[kMaxS];
        #pragma unroll
        for (int r = 0; r < kMaxS; ++r) {       // static r -> topPix stays in registers
            topPix[r] = 0;
            if (r < S) {
                unsigned long long my = c[0];
                #pragma unroll
                for (int k = 1; k < 16; ++k) my = u64max(my, c[k]);
                const unsigned long long w = waveMax64(my);
                topPix[r] = (int)(~(unsigned int)w);
                #pragma unroll
                for (int k = 0; k < 16; ++k) if (c[k] == w) c[k] = 0ull;
            }
        }

        int idx0 = idxp[0];
        idx0 = idx0 < 0 ? 0 : (idx0 > 2 ? 2 : idx0);
        const int v1 = (idx0 == 0) ? 1 : 0;
        const int v2 = (idx0 == 2) ? 1 : 2;

        // gather 3 views x S vectors; all loads issued before any reduction
        float cc[kMaxS], x1[kMaxS], x2[kMaxS];
        #pragma unroll
        for (int s = 0; s < kMaxS; ++s) {
            cc[s] = 0.f; x1[s] = 0.f; x2[s] = 0.f;
            if (s < S) {
                const size_t off = (size_t)lane * kHW + (size_t)(unsigned int)topPix[s];
                cc[s] = proj[((size_t)(idx0 * kB + b) * kD) * kHW + off];
                x1[s] = proj[((size_t)(v1  * kB + b) * kD) * kHW + off];
                x2[s] = proj[((size_t)(v2  * kB + b) * kD) * kHW + off];
            }
        }
        // L2-normalize (matches p / max(norm, 1e-12))
        float cv[kMaxS], ap[kMaxS];
        #pragma unroll
        for (int s = 0; s < kMaxS; ++s) {
            cv[s] = 0.f; ap[s] = 0.f;
            if (s < S) {
                const float c0 = cc[s] / fmaxf(sqrtf(wave_sum(cc[s] * cc[s])), kEpsNorm);
                const float a1 = x1[s] / fmaxf(sqrtf(wave_sum(x1[s] * x1[s])), kEpsNorm);
                const float a2 = x2[s] / fmaxf(sqrtf(wave_sum(x2[s] * x2[s])), kEpsNorm);
                cv[s] = c0; ap[s] = a1 + a2;
            }
        }
        // positive: exp((c.p1 + c.p2)/tau)
        float pl[kMaxS];
        #pragma unroll
        for (int s = 0; s < kMaxS; ++s) {
            pl[s] = 0.f;
            if (s < S) pl[s] = expf(wave_sum(cv[s] * ap[s]) / kTau);
        }
        // negatives via symmetry: neg[j] = sum_{i!=j} exp(c_i.c_j/tau)
        float neg[kMaxS];
        #pragma unroll
        for (int s = 0; s < kMaxS; ++s) neg[s] = 0.f;
        #pragma unroll
        for (int i = 0; i < kMaxS; ++i) {
            if (i < S) {
                #pragma unroll
                for (int j = i + 1; j < kMaxS; ++j) {
                    if (j < S) {
                        const float e = expf(wave_sum(cv[i] * cv[j]) / kTau);
                        neg[i] += e; neg[j] += e;
                    }
                }
            }
        }
        float acc = 0.f;
        #pragma unroll
        for (int s = 0; s < kMaxS; ++s)
            if (s < S) acc += -logf(pl[s] / (pl[s] + neg[s] + kEpsDen));
        if (lane == 0) per_b[b] = acc / (float)S;
    }

    grid.sync();

    // ================= Phase C: deterministic final sum =================
    if (blockIdx.x == 0 && t == 0) {
        float s = 0.f;
        for (int i = 0; i < kB; ++i) s += per_b[i];
        out[0] = s / (float)kB;
    }
}

extern "C" void kernel_launch(void* const* d_in, const int* in_sizes, int n_in,
                              void* d_out, int out_size, void* d_ws, size_t ws_size,
                              hipStream_t stream) {
    const float* pred = (const float*)d_in[0];
    const float* proj = (const float*)d_in[1];
    // d_in[2] mask, d_in[3] pseudo_label: unused by the reference
    const int* idxp  = (const int*)d_in[4];
    const int* snump = (const int*)d_in[5];
    float* out = (float*)d_out;

    char* ws = (char*)d_ws;
    unsigned long long* cand = (unsigned long long*)ws;                  // 24576 u64
    float* per_b = (float*)(ws + (size_t)kB * kSlotsPerBatch * 8);       // 24 f32

    void* args[] = {(void*)&pred, (void*)&proj, (void*)&idxp, (void*)&snump,
                    (void*)&cand, (void*)&per_b, (void*)&out};
    hipLaunchCooperativeKernel((const void*)k_fused,
                               dim3(kB * kNChunk), dim3(256), args, 0, stream);
}

// Round 9
// 26.900 us; speedup vs baseline: 5.8374x; 5.8374x over previous
//
#include <hip/hip_runtime.h>
#include <float.h>
#include <limits.h>
#include <math.h>

// Fixed problem shapes
constexpr int kB = 24;
constexpr int kC = 4;
constexpr int kHW = 65536;              // 256*256
constexpr int kD = 64;
constexpr int kNChunk = 32;
constexpr int kChunk = kHW / kNChunk;   // 2048 pixels per chunk-block
constexpr int kWaves = 4;               // waves per K1 block
constexpr int kMaxS = 8;                // supports sample_num <= 8 (actual 5)
constexpr int kSlotsPerBatch = kNChunk * kWaves * kMaxS;   // 1024 candidate slots
constexpr float kTau = 0.07f;
constexpr float kEpsLog = 1e-6f;
constexpr float kEpsDen = 1e-8f;
constexpr float kEpsNorm = 1e-12f;

// ---- packed ordering key: high32 = monotone-mapped float (desc), low32 = ~pix (idx asc) ----
__device__ __forceinline__ unsigned long long packKey(float v, unsigned int pix) {
    unsigned int x = __float_as_uint(v);
    unsigned int m = x ^ (((unsigned int)((int)x >> 31)) | 0x80000000u);  // branchless monotone map
    return ((unsigned long long)m << 32) | (unsigned long long)(~pix);
}

__device__ __forceinline__ unsigned long long u64max(unsigned long long a, unsigned long long b) {
    return a > b ? a : b;
}

__device__ __forceinline__ unsigned long long shfl_xor_u64(unsigned long long k, int m) {
    int lo = __shfl_xor((int)(unsigned int)k, m, 64);
    int hi = __shfl_xor((int)(unsigned int)(k >> 32), m, 64);
    return ((unsigned long long)(unsigned int)hi << 32) | (unsigned long long)(unsigned int)lo;
}

__device__ __forceinline__ unsigned long long waveMax64(unsigned long long k) {
    #pragma unroll
    for (int o = 32; o > 0; o >>= 1) k = u64max(k, shfl_xor_u64(k, o));
    return k;
}

__device__ __forceinline__ float wave_sum(float x) {
    #pragma unroll
    for (int o = 32; o > 0; o >>= 1) x += __shfl_xor(x, o, 64);
    return x;
}

// ---------------------------------------------------------------------------
// K1: per-wave top-S of unc[j] = sum_c x*log(x+eps) over its 512 pixels.
// NO barriers, NO LDS, NO block merge: 3072 independent waves, each writes
// its top-S keys to its own candidate slot group. Block 0 also zeroes the
// K2 election counter (plain store; kernel boundary orders it before K2).
// grid: kB*kNChunk blocks x 256 threads.
// ---------------------------------------------------------------------------
__global__ __launch_bounds__(256) void k_topk(
        const float* __restrict__ pred, const int* __restrict__ snum,
        unsigned long long* __restrict__ cand,
        unsigned int* __restrict__ done_ctr) {
    if (blockIdx.x == 0 && threadIdx.x == 0) *done_ctr = 0u;   // replaces memset node
    int S = snum[0];
    S = S < 1 ? 1 : (S > kMaxS ? kMaxS : S);
    const int t = threadIdx.x;
    const int lane = t & 63;
    const int wave = t >> 6;
    const int b = blockIdx.x / kNChunk;
    const int chunk = blockIdx.x % kNChunk;
    const int j0 = chunk * kChunk + t * 8;              // 8 consecutive pixels/thread
    const float* pb = pred + (size_t)b * kC * kHW + j0;

    float u[8];
    #pragma unroll
    for (int i = 0; i < 8; ++i) u[i] = 0.f;
    #pragma unroll
    for (int c = 0; c < kC; ++c) {
        float4 a = *reinterpret_cast<const float4*>(pb + (size_t)c * kHW);
        float4 d = *reinterpret_cast<const float4*>(pb + (size_t)c * kHW + 4);
        u[0] += a.x * __logf(a.x + kEpsLog);
        u[1] += a.y * __logf(a.y + kEpsLog);
        u[2] += a.z * __logf(a.z + kEpsLog);
        u[3] += a.w * __logf(a.w + kEpsLog);
        u[4] += d.x * __logf(d.x + kEpsLog);
        u[5] += d.y * __logf(d.y + kEpsLog);
        u[6] += d.z * __logf(d.z + kEpsLog);
        u[7] += d.w * __logf(d.w + kEpsLog);
    }
    unsigned long long key[8];
    #pragma unroll
    for (int i = 0; i < 8; ++i) key[i] = packKey(u[i], (unsigned int)(j0 + i));

    // S rounds of wave argmax + removal; lane0 writes each winner.
    unsigned long long* myCand = cand + ((size_t)blockIdx.x * kWaves + wave) * kMaxS;
    for (int r = 0; r < S; ++r) {
        unsigned long long my = key[0];
        #pragma unroll
        for (int i = 1; i < 8; ++i) my = u64max(my, key[i]);
        const unsigned long long w = waveMax64(my);
        if (lane == 0) myCand[r] = w;
        #pragma unroll
        for (int i = 0; i < 8; ++i) if (key[i] == w) key[i] = 0ull;
    }
}

// ---------------------------------------------------------------------------
// K2: 24 blocks x 64 threads (1 wave each). Block b: merge batch b's 1024
// candidate slots -> top-S pixels, gather 3 views' vectors (lane = feature d),
// normalize, contrastive loss -> per_b[b] (agent-scope atomic store).
// LAST finishing block (agent-scope ACQ_REL election) does the deterministic
// serial b=0..23 sum -> out[0]. 24 atomics total.
// ---------------------------------------------------------------------------
__global__ __launch_bounds__(64) void k_loss_final(
        const float* __restrict__ proj, const int* __restrict__ idxp,
        const int* __restrict__ snum, const unsigned long long* __restrict__ cand,
        float* __restrict__ per_b, unsigned int* __restrict__ done_ctr,
        float* __restrict__ out) {
    int S = snum[0];
    S = S < 1 ? 1 : (S > kMaxS ? kMaxS : S);
    const int b = blockIdx.x;
    const int lane = threadIdx.x;

    // ---- merge this batch's 1024 candidate slots (16 per lane, coalesced) ----
    const unsigned long long* bc = cand + (size_t)b * kSlotsPerBatch;
    unsigned long long c[16];
    #pragma unroll
    for (int k = 0; k < 16; ++k) {
        const int sid = lane + 64 * k;
        const unsigned long long v = bc[sid];
        c[k] = ((sid & (kMaxS - 1)) < S) ? v : 0ull;   // mask slots K1 never wrote
    }
    int topPix[kMaxS];
    #pragma unroll
    for (int r = 0; r < kMaxS; ++r) {       // static r -> topPix stays in registers
        topPix[r] = 0;
        if (r < S) {
            unsigned long long my = c[0];
            #pragma unroll
            for (int k = 1; k < 16; ++k) my = u64max(my, c[k]);
            const unsigned long long w = waveMax64(my);
            topPix[r] = (int)(~(unsigned int)w);
            #pragma unroll
            for (int k = 0; k < 16; ++k) if (c[k] == w) c[k] = 0ull;
        }
    }

    int idx0 = idxp[0];
    idx0 = idx0 < 0 ? 0 : (idx0 > 2 ? 2 : idx0);
    const int v1 = (idx0 == 0) ? 1 : 0;
    const int v2 = (idx0 == 2) ? 1 : 2;

    // ---- gather 3 views x S vectors; all loads issued before any reduction ----
    float cc[kMaxS], x1[kMaxS], x2[kMaxS];
    #pragma unroll
    for (int s = 0; s < kMaxS; ++s) {
        cc[s] = 0.f; x1[s] = 0.f; x2[s] = 0.f;
        if (s < S) {
            const size_t off = (size_t)lane * kHW + (size_t)(unsigned int)topPix[s];
            cc[s] = proj[((size_t)(idx0 * kB + b) * kD) * kHW + off];
            x1[s] = proj[((size_t)(v1  * kB + b) * kD) * kHW + off];
            x2[s] = proj[((size_t)(v2  * kB + b) * kD) * kHW + off];
        }
    }
    // ---- L2-normalize (matches p / max(norm, 1e-12)) ----
    float cv[kMaxS], ap[kMaxS];
    #pragma unroll
    for (int s = 0; s < kMaxS; ++s) {
        cv[s] = 0.f; ap[s] = 0.f;
        if (s < S) {
            const float c0 = cc[s] / fmaxf(sqrtf(wave_sum(cc[s] * cc[s])), kEpsNorm);
            const float a1 = x1[s] / fmaxf(sqrtf(wave_sum(x1[s] * x1[s])), kEpsNorm);
            const float a2 = x2[s] / fmaxf(sqrtf(wave_sum(x2[s] * x2[s])), kEpsNorm);
            cv[s] = c0; ap[s] = a1 + a2;
        }
    }
    // ---- positive: exp((c.p1 + c.p2)/tau) ----
    float pl[kMaxS];
    #pragma unroll
    for (int s = 0; s < kMaxS; ++s) {
        pl[s] = 0.f;
        if (s < S) pl[s] = expf(wave_sum(cv[s] * ap[s]) / kTau);
    }
    // ---- negatives via symmetry: neg[j] = sum_{i!=j} exp(c_i.c_j/tau) ----
    float neg[kMaxS];
    #pragma unroll
    for (int s = 0; s < kMaxS; ++s) neg[s] = 0.f;
    #pragma unroll
    for (int i = 0; i < kMaxS; ++i) {
        if (i < S) {
            #pragma unroll
            for (int j = i + 1; j < kMaxS; ++j) {
                if (j < S) {
                    const float e = expf(wave_sum(cv[i] * cv[j]) / kTau);
                    neg[i] += e; neg[j] += e;
                }
            }
        }
    }
    float acc = 0.f;
    #pragma unroll
    for (int s = 0; s < kMaxS; ++s)
        if (s < S) acc += -logf(pl[s] / (pl[s] + neg[s] + kEpsDen));

    if (lane == 0) {
        // agent-scope atomic store -> visible across XCDs once counter released
        __hip_atomic_store(&per_b[b], acc / (float)S,
                           __ATOMIC_RELAXED, __HIP_MEMORY_SCOPE_AGENT);
        // release my store, acquire everyone else's
        const unsigned int old = __hip_atomic_fetch_add(
                done_ctr, 1u, __ATOMIC_ACQ_REL, __HIP_MEMORY_SCOPE_AGENT);
        if (old == (unsigned int)(kB - 1)) {
            // last block: deterministic serial sum (fixed fp order b=0..23)
            float s = 0.f;
            for (int i = 0; i < kB; ++i)
                s += __hip_atomic_load(&per_b[i], __ATOMIC_RELAXED,
                                       __HIP_MEMORY_SCOPE_AGENT);
            out[0] = s / (float)kB;
        }
    }
}

extern "C" void kernel_launch(void* const* d_in, const int* in_sizes, int n_in,
                              void* d_out, int out_size, void* d_ws, size_t ws_size,
                              hipStream_t stream) {
    const float* pred = (const float*)d_in[0];
    const float* proj = (const float*)d_in[1];
    // d_in[2] mask, d_in[3] pseudo_label: unused by the reference
    const int* idxp  = (const int*)d_in[4];
    const int* snump = (const int*)d_in[5];
    float* out = (float*)d_out;

    char* ws = (char*)d_ws;
    unsigned int* done_ctr = (unsigned int*)ws;                       // 1 u32 (pad 128)
    unsigned long long* cand = (unsigned long long*)(ws + 128);       // 24576 u64
    float* per_b = (float*)(ws + 128 + (size_t)kB * kSlotsPerBatch * 8);  // 24 f32

    k_topk<<<kB * kNChunk, 256, 0, stream>>>(pred, snump, cand, done_ctr);
    k_loss_final<<<kB, 64, 0, stream>>>(proj, idxp, snump, cand, per_b, done_ctr, out);
}